// Round 11
// baseline (283.295 us; speedup 1.0000x reference)
//
#include <hip/hip_runtime.h>
#include <hip/hip_bf16.h>
#include <cfloat>

#define DIM 690
#define NCHUNK 22
#define HCHUNK 11         // k-chunks per half
#define N_CLS 53
#define YLD 64            // y row stride in shorts (128 B rows)
#define BM 16             // rows per slab
#define HLD 360           // LDS half-row stride in shorts (720 B, 16B-aligned, 2-way-free b128)
#define AWLD 704          // aw row stride in shorts (zero-padded)
#define GRID_SCORE 1280   // 5 blocks/CU x 256 CU (persistent)
#define NSLAB 16384       // 262144 / BM

typedef short bf16x8 __attribute__((ext_vector_type(8)));
typedef float f32x4  __attribute__((ext_vector_type(4)));

static __device__ __forceinline__ unsigned int f2bf(float f) {
    __hip_bfloat16 h = __float2bfloat16(f);
    return (unsigned int)*reinterpret_cast<unsigned short*>(&h);
}
static __device__ __forceinline__ float bflo(unsigned int v) {
    union { unsigned int u; float f; } c; c.u = v << 16; return c.f;
}
static __device__ __forceinline__ float bfhi(unsigned int v) {
    union { unsigned int u; float f; } c; c.u = v & 0xFFFF0000u; return c.f;
}

// lgkmcnt-only barrier: ds_writes made visible, but in-flight global loads
// (sreg prefetch, y stores) cross freely — avoids __syncthreads' vmcnt(0) drain.
#define BAR() do { asm volatile("s_waitcnt lgkmcnt(0)" ::: "memory"); \
                   __builtin_amdgcn_s_barrier(); } while (0)

// ---------------------------------------------------------------------------
// P0: pack
//  wbp — fragment-ordered B: wbp[((kk*4+kg)*64 + c)*8 + j] = bf16(rel_w[c][k]),
//        k = kk*32 + kg*8 + j, zero-padded (c>=53 or k>=690)
//  awb — row-major bf16(att*rel) [53][704] (fp32 product), zero-padded
// ---------------------------------------------------------------------------
__global__ __launch_bounds__(256) void prep_kernel(
    const float* __restrict__ rel_w, const float* __restrict__ att_w,
    unsigned short* __restrict__ wbp, unsigned short* __restrict__ awb)
{
    int idx = blockIdx.x * blockDim.x + threadIdx.x;
    const int NW = NCHUNK * 4 * 512;   // 45056
    const int NA = N_CLS * AWLD;       // 37312
    if (idx < NW) {
        int kkg = idx >> 9;            // kk*4+kg
        int rem = idx & 511;
        int c = rem >> 3, j = rem & 7;
        int k = (kkg >> 2) * 32 + (kkg & 3) * 8 + j;
        float v = (c < N_CLS && k < DIM) ? rel_w[c * DIM + k] : 0.f;
        wbp[idx] = (unsigned short)f2bf(v);
    } else if (idx < NW + NA) {
        int i2 = idx - NW;
        int c = i2 / AWLD, k = i2 - c * AWLD;
        float v = (k < DIM) ? att_w[c * DIM + k] * rel_w[c * DIM + k] : 0.f;
        awb[i2] = (unsigned short)f2bf(v);
    }
}

// ---------------------------------------------------------------------------
// K1: fused score GEMM + staged-register attention logit, K-SPLIT pipeline.
// Persistent blocks, BM=16 slabs, halves of 352 cols double-buffered
// (xs half-buffers 11.5 KB each -> 5 blocks/CU, 20 waves/CU).
// Phase (per half): compute(xs[p]) -> logit-dot(sreg, drains prefetch) ->
// write xs[p^1] -> issue next half's loads -> lgkmcnt-barrier (loads stay
// in flight across it and are consumed one full phase later).
// h1 tail (global cols 690..703) auto-zeroed via bounds-checked loads.
// A/B frag: k = 8*(lane>>4)+j, A row / B col = lane&15.
// D frag: col = lane&15, row = (lane>>4)*4 + reg.
// ---------------------------------------------------------------------------
__global__ __launch_bounds__(256, 5) void score_kernel(
    const float* __restrict__ x,
    const unsigned short* __restrict__ wbp,
    const unsigned short* __restrict__ awb,
    const int* __restrict__ query,
    unsigned short* __restrict__ y,
    float* __restrict__ logit)
{
    __shared__ unsigned short xs[2 * BM * HLD];

    const int t = threadIdx.x;
    const int lane = t & 63;
    const int wv = t >> 6;
    const int r = lane & 15, kg = lane >> 4;
    const int srow = t >> 4, sub = t & 15;   // stage: 16 threads per row

    float4 sreg[6];
    float lg = 0.f;

    // h passed as literal -> branches fold at compile time.
    auto load_half = [&](int s, int h) {
        const float* xrow = x + ((size_t)s * BM + srow) * DIM + h * 352;
        #pragma unroll
        for (int i = 0; i < 5; ++i)
            sreg[i] = *reinterpret_cast<const float4*>(xrow + i * 64 + sub * 4);
        if (sub < 8) {
            if (h == 0 || sub < 4)
                sreg[5] = *reinterpret_cast<const float4*>(xrow + 320 + sub * 4);
            else if (sub == 4) {               // global cols 688..691 -> load 2
                float2 v = *reinterpret_cast<const float2*>(xrow + 336);
                sreg[5] = make_float4(v.x, v.y, 0.f, 0.f);
            } else
                sreg[5] = make_float4(0.f, 0.f, 0.f, 0.f);
        } else
            sreg[5] = make_float4(0.f, 0.f, 0.f, 0.f);
    };
    // logit partial for (s,h) from sreg (fp32) vs bf16 aw row (L2-hot,
    // row-shared by the row's 16 threads -> coalesced uint2 loads).
    auto dot_half = [&](int s, int h) {
        const int q = query[s * BM + srow];
        const unsigned short* awrow = awb + (size_t)q * AWLD + h * 352;
        float l = 0.f;
        #pragma unroll
        for (int i = 0; i < 5; ++i) {
            uint2 v = *reinterpret_cast<const uint2*>(awrow + i * 64 + sub * 4);
            l += sreg[i].x * bflo(v.x) + sreg[i].y * bfhi(v.x)
               + sreg[i].z * bflo(v.y) + sreg[i].w * bfhi(v.y);
        }
        if (sub < 8) {
            uint2 v = *reinterpret_cast<const uint2*>(awrow + 320 + sub * 4);
            l += sreg[5].x * bflo(v.x) + sreg[5].y * bfhi(v.x)
               + sreg[5].z * bflo(v.y) + sreg[5].w * bfhi(v.y);
        }
        lg += l;
    };
    auto write_half = [&](int b) {
        unsigned short* base = xs + b * (BM * HLD) + srow * HLD;
        #pragma unroll
        for (int i = 0; i < 5; ++i) {
            uint2 p = make_uint2(f2bf(sreg[i].x) | (f2bf(sreg[i].y) << 16),
                                 f2bf(sreg[i].z) | (f2bf(sreg[i].w) << 16));
            *reinterpret_cast<uint2*>(base + i * 64 + sub * 4) = p;
        }
        if (sub < 8) {
            uint2 p = make_uint2(f2bf(sreg[5].x) | (f2bf(sreg[5].y) << 16),
                                 f2bf(sreg[5].z) | (f2bf(sreg[5].w) << 16));
            *reinterpret_cast<uint2*>(base + 320 + sub * 4) = p;
        }
    };

    const unsigned short* fb = wbp + (size_t)((kg * 64 + wv * 16 + r) * 8);

    int slab = blockIdx.x;
    load_half(slab, 0);
    dot_half(slab, 0);
    write_half(0);
    load_half(slab, 1);
    BAR();

    while (true) {
        const int next = slab + GRID_SCORE;
        const bool has_next = next < NSLAB;

        // ---- phase A: compute h0 from xs[0]; sreg = (slab,h1) in flight ----
        f32x4 acc = {0.f, 0.f, 0.f, 0.f};
        {
            const unsigned short* xbase = xs + r * HLD;
            #pragma unroll
            for (int kk = 0; kk < HCHUNK; ++kk) {
                bf16x8 af = *reinterpret_cast<const bf16x8*>(xbase + kk * 32 + kg * 8);
                bf16x8 bw = *reinterpret_cast<const bf16x8*>(fb + (size_t)kk * 2048);
                acc = __builtin_amdgcn_mfma_f32_16x16x32_bf16(af, bw, acc, 0, 0, 0);
            }
        }
        dot_half(slab, 1);                 // lg complete for this slab
        write_half(1);
        if (has_next) load_half(next, 0);  // crosses barrier in flight
        BAR();

        // ---- phase B: compute h1 from xs[1]; sreg = (next,h0) in flight ----
        {
            const unsigned short* xbase = xs + (BM * HLD) + r * HLD;
            #pragma unroll
            for (int kk = 0; kk < HCHUNK; ++kk) {
                bf16x8 af = *reinterpret_cast<const bf16x8*>(xbase + kk * 32 + kg * 8);
                bf16x8 bw = *reinterpret_cast<const bf16x8*>(fb + (size_t)(HCHUNK + kk) * 2048);
                acc = __builtin_amdgcn_mfma_f32_16x16x32_bf16(af, bw, acc, 0, 0, 0);
            }
        }
        {
            const int rowBase = slab * BM;
            #pragma unroll
            for (int reg = 0; reg < 4; ++reg)
                y[(size_t)(rowBase + kg * 4 + reg) * YLD + wv * 16 + r] =
                    (unsigned short)f2bf(acc[reg]);
            float l = lg;
            l += __shfl_xor(l, 1);
            l += __shfl_xor(l, 2);
            l += __shfl_xor(l, 4);
            l += __shfl_xor(l, 8);
            if (sub == 0) logit[rowBase + srow] = l;
        }
        if (!has_next) break;
        lg = 0.f;
        dot_half(next, 0);
        write_half(0);
        load_half(next, 1);
        BAR();
        slab = next;
    }
}

// ---------------------------------------------------------------------------
// K2: one block (4 waves) per bag. Wave lanes: cq=lane&15 -> cols 4cq..4cq+3
// (uint2 = 4 bf16), rq=lane>>4 -> row offset. Per instruction: 4 rows x
// 128 B contiguous. Col-indexed LDS reduce across waves.
// ---------------------------------------------------------------------------
__global__ __launch_bounds__(256) void bag_kernel(
    const unsigned short* __restrict__ y,
    const float* __restrict__ logit,
    const float* __restrict__ bias,
    const int* __restrict__ scope,
    float* __restrict__ out)
{
    const int bag = blockIdx.x;
    const int t = threadIdx.x, lane = t & 63, wv = t >> 6;
    const int s = scope[bag], e = scope[bag + 1];

    __shared__ float red[4][64];

    float m = -FLT_MAX;
    for (int i = s + lane; i < e; i += 64) m = fmaxf(m, logit[i]);
    #pragma unroll
    for (int off = 32; off > 0; off >>= 1) m = fmaxf(m, __shfl_xor(m, off));

    float sum = 0.f;
    for (int i = s + lane; i < e; i += 64) sum += __expf(logit[i] - m);
    #pragma unroll
    for (int off = 32; off > 0; off >>= 1) sum += __shfl_xor(sum, off);
    const float inv = 1.f / sum;

    const int cq = lane & 15;          // col quad: cols 4cq..4cq+3
    const int rq = lane >> 4;          // row offset 0..3
    const uint2* yu = reinterpret_cast<const uint2*>(y);

    float a0 = 0.f, a1 = 0.f, a2 = 0.f, a3 = 0.f;
    for (int base = s + wv * 4; base < e; base += 16) {
        int row = base + rq;
        if (row < e) {
            float w = __expf(logit[row] - m) * inv;
            uint2 v = yu[(size_t)row * (YLD / 4) + cq];
            a0 += w * bflo(v.x);
            a1 += w * bfhi(v.x);
            a2 += w * bflo(v.y);
            a3 += w * bfhi(v.y);
        }
    }
    a0 += __shfl_xor(a0, 16); a0 += __shfl_xor(a0, 32);
    a1 += __shfl_xor(a1, 16); a1 += __shfl_xor(a1, 32);
    a2 += __shfl_xor(a2, 16); a2 += __shfl_xor(a2, 32);
    a3 += __shfl_xor(a3, 16); a3 += __shfl_xor(a3, 32);
    if (lane < 16) {
        red[wv][4 * lane + 0] = a0;
        red[wv][4 * lane + 1] = a1;
        red[wv][4 * lane + 2] = a2;
        red[wv][4 * lane + 3] = a3;
    }
    __syncthreads();
    if (t < N_CLS)
        out[(size_t)bag * N_CLS + t] =
            red[0][t] + red[1][t] + red[2][t] + red[3][t] + bias[t];
}

// ---------------------------------------------------------------------------
extern "C" void kernel_launch(void* const* d_in, const int* in_sizes, int n_in,
                              void* d_out, int out_size, void* d_ws, size_t ws_size,
                              hipStream_t stream)
{
    const float* x     = (const float*)d_in[0];
    const float* rel_w = (const float*)d_in[1];
    const float* att_w = (const float*)d_in[2];
    const float* bias  = (const float*)d_in[3];
    const int*   query = (const int*)d_in[4];
    const int*   scope = (const int*)d_in[5];
    float*       out   = (float*)d_out;

    const int n_sent = in_sizes[0] / DIM;      // 262144
    const int n_bags = in_sizes[5] - 1;        // 8192

    // workspace layout
    const int NW = NCHUNK * 4 * 512;                           // 45056 shorts
    const int NA = N_CLS * AWLD;                               // 37312 shorts
    unsigned short* wbp   = (unsigned short*)d_ws;             // NW
    unsigned short* awb   = wbp + NW;                          // NA
    float*          logit = (float*)(awb + NA);                // n_sent
    unsigned short* y     = (unsigned short*)(logit + n_sent); // n_sent*YLD

    prep_kernel<<<(NW + NA + 255) / 256, 256, 0, stream>>>(rel_w, att_w, wbp, awb);

    score_kernel<<<GRID_SCORE, 256, 0, stream>>>(x, wbp, awb, query, y, logit);

    bag_kernel<<<n_bags, 256, 0, stream>>>(y, logit, bias, scope, out);
}